// Round 1
// 336.538 us; speedup vs baseline: 1.1257x; 1.1257x over previous
//
#include <hip/hip_runtime.h>

#define BB 16
#define CC 32
#define HH 256
#define WW 256

#define TW 32     // tile width (pixels) = MFMA N
#define TH 8      // tile rows per block (4 waves x 2 rows)
#define NT 4      // y-subtiles per block (tile loop)
#define CIP 36    // padded ci per (y,x) in LDS: 72 B -> 2-way banks (free), 8B-aligned

typedef short bf16x8 __attribute__((ext_vector_type(8)));
typedef float f32x16 __attribute__((ext_vector_type(16)));

struct alignas(8)  U2 { unsigned x, y; };
struct alignas(16) U4 { U2 lo, hi; };

__device__ __forceinline__ unsigned short f2bf(float f) {
    unsigned u = __float_as_uint(f);
    u += 0x7fffu + ((u >> 16) & 1u);   // RNE
    return (unsigned short)(u >> 16);
}

// HW packed f32->bf16 (RNE), lo = first operand.
__device__ __forceinline__ unsigned cvtpk(float lo, float hi) {
    unsigned r;
    asm("v_cvt_pk_bf16_f32 %0, %1, %2" : "=v"(r) : "v"(lo), "v"(hi));
    return r;
}

// Pre-swizzle weights into per-lane MFMA A-fragment order, bf16:
// wq[layer][st(18)][half(2)][n=co(32)][j(8)], value = w[co][ci][pos]
// with pos = st>>1 (kh*3+kw), ci = (st&1)*16 + half*8 + j.
__global__ void wprep(const float* __restrict__ w1, const float* __restrict__ w2,
                      unsigned short* __restrict__ wq) {
    int idx = blockIdx.x * 256 + threadIdx.x;   // 0..9215
    if (idx >= 18 * 2 * 32 * 8) return;
    int j    = idx & 7;
    int n    = (idx >> 3) & 31;
    int half = (idx >> 8) & 1;
    int st   = idx >> 9;
    int s = st & 1, pos = st >> 1;
    int ci = s * 16 + half * 8 + j;
    int src = (n * CC + ci) * 9 + pos;
    wq[idx]        = f2bf(w1[src]);
    wq[9216 + idx] = f2bf(w2[src]);
}

// Stage one (TH+2) x (TW+2) x 32ci input tile into LDS (channels-last bf16).
template<bool FIRST>
__device__ __forceinline__ void stage_tile(const void* __restrict__ in, int b, int y0, int x0, int t,
                                           unsigned short (&xs)[TH + 2][TW + 2][CIP])
{
    if (FIRST) {
        // fp32 NCHW x: one pixel per thread, 32 coalesced dword loads off a scalar base,
        // packed cvt, 8x ds_write_b64.
        const float* xb = (const float*)in + (size_t)b * CC * HH * WW;
        #pragma unroll
        for (int rep = 0; rep < 2; ++rep) {
            int p = rep * 256 + t;
            if (p < (TH + 2) * (TW + 2)) {
                int y  = p / (TW + 2);
                int xx = p - y * (TW + 2);
                int gy = y0 + y - 1, gx = x0 + xx - 1;
                bool inb = (gy >= 0 && gy < HH && gx >= 0 && gx < WW);
                int off = gy * WW + gx;          // only used when inb
                #pragma unroll
                for (int c16 = 0; c16 < 2; ++c16) {
                    float v[16];
                    #pragma unroll
                    for (int j = 0; j < 16; ++j) v[j] = 0.f;
                    if (inb) {
                        #pragma unroll
                        for (int j = 0; j < 16; ++j)
                            v[j] = xb[(c16 * 16 + j) * (HH * WW) + off];
                    }
                    #pragma unroll
                    for (int k = 0; k < 4; ++k) {
                        U2 w;
                        w.x = cvtpk(v[4 * k + 0], v[4 * k + 1]);
                        w.y = cvtpk(v[4 * k + 2], v[4 * k + 3]);
                        *(U2*)&xs[y][xx][c16 * 16 + k * 4] = w;
                    }
                }
            }
        }
    } else {
        // bf16 NHWC h1: 16-B vector loads, scalar base + 32-bit offset.
        const unsigned short* hb = (const unsigned short*)in + (size_t)b * HH * WW * CC;
        #pragma unroll
        for (int rep = 0; rep < 6; ++rep) {
            int idx = rep * 256 + t;
            if (idx < (TH + 2) * (TW + 2) * 4) {
                int q = idx & 3;
                int p = idx >> 2;
                int y  = p / (TW + 2);
                int xx = p - y * (TW + 2);
                int gy = y0 + y - 1, gx = x0 + xx - 1;
                U4 v; v.lo = {0u, 0u}; v.hi = {0u, 0u};
                if (gy >= 0 && gy < HH && gx >= 0 && gx < WW)
                    v = *(const U4*)(hb + ((gy * WW + gx) * CC + q * 8));
                *(U2*)&xs[y][xx][q * 8]     = v.lo;
                *(U2*)&xs[y][xx][q * 8 + 4] = v.hi;
            }
        }
    }
}

// Implicit-GEMM conv3x3 (SAME) with fused bias*gate + relu.
// FIRST: in = fp32 NCHW x, out = bf16 NHWC h1.
// !FIRST: in = bf16 NHWC h1, out = fp32 NCHW (+= resid).
template<bool FIRST>
__global__ __launch_bounds__(256)
void conv_mfma(const void* __restrict__ in,
               const unsigned short* __restrict__ wq,
               const float* __restrict__ bias,
               const float* __restrict__ gate,
               const float* __restrict__ resid,
               void* __restrict__ out)
{
    __shared__ unsigned short xs[TH + 2][TW + 2][CIP];   // 24480 B
    __shared__ float gs[CC], bs[CC];

    const int t     = threadIdx.x;
    const int b     = blockIdx.z;
    const int x0    = blockIdx.x * TW;
    const int ybase = blockIdx.y * (TH * NT);

    if (t < CC) {
        float gv = gate[b * CC + t];
        gs[t] = gv > 0.f ? gv : 0.f;
        bs[t] = bias[t];
    }

    const int lane = t & 63;
    const int wv   = t >> 6;       // wave 0..3
    const int col  = lane & 31;    // MFMA n (pixel) / A m (co) lane index
    const int half = lane >> 5;
    const int r0 = wv * 2, r1 = wv * 2 + 1;

    // Weight fragments: loaded ONCE per block, reused across NT tiles.
    bf16x8 wf[18];
    #pragma unroll
    for (int st = 0; st < 18; ++st) {
        U4 w = ((const U4*)wq)[(st * 2 + half) * 32 + col];
        wf[st] = __builtin_bit_cast(bf16x8, w);
    }

    stage_tile<FIRST>(in, b, ybase, x0, t, xs);

    #pragma unroll 1
    for (int s = 0; s < NT; ++s) {
        const int y0 = ybase + s * TH;
        __syncthreads();   // staging of tile s complete

        // ---- K loop: 18 steps of 16 (pos = kh*3+kw outer, ci-half inner) ----
        f32x16 acc0 = {0,0,0,0,0,0,0,0,0,0,0,0,0,0,0,0};
        f32x16 acc1 = {0,0,0,0,0,0,0,0,0,0,0,0,0,0,0,0};
        #pragma unroll
        for (int st = 0; st < 18; ++st) {
            const int pos = st >> 1, sb = st & 1;
            const int kh = pos / 3, kw = pos - kh * 3;
            const int ci0 = sb * 16 + half * 8;
            U4 xa, xb;
            xa.lo = *(const U2*)&xs[r0 + kh][col + kw][ci0];
            xa.hi = *(const U2*)&xs[r0 + kh][col + kw][ci0 + 4];
            xb.lo = *(const U2*)&xs[r1 + kh][col + kw][ci0];
            xb.hi = *(const U2*)&xs[r1 + kh][col + kw][ci0 + 4];
            acc0 = __builtin_amdgcn_mfma_f32_32x32x16_bf16(wf[st], __builtin_bit_cast(bf16x8, xa), acc0, 0, 0, 0);
            acc1 = __builtin_amdgcn_mfma_f32_32x32x16_bf16(wf[st], __builtin_bit_cast(bf16x8, xb), acc1, 0, 0, 0);
        }

        __syncthreads();   // all ds_reads of tile s done; LDS free for tile s+1

        // Issue next tile's staging BEFORE the epilogue: HBM latency hides
        // under the epilogue's cvt/store work.
        if (s + 1 < NT) stage_tile<FIRST>(in, b, y0 + TH, x0, t, xs);

        // ---- epilogue: D[m=co][n=pixel], col = lane&31, co = (reg&3)+8*(reg>>2)+4*half ----
        if (FIRST) {
            unsigned short* ob = (unsigned short*)out + (size_t)b * HH * WW * CC;
            int p0 = ((y0 + r0) * WW + x0 + col) * CC;
            int p1 = ((y0 + r1) * WW + x0 + col) * CC;
            #pragma unroll
            for (int g = 0; g < 4; ++g) {
                int c0 = 8 * g + 4 * half;   // regs 4g..4g+3 -> consecutive co
                float a0 = fmaxf((acc0[4 * g + 0] + bs[c0 + 0]) * gs[c0 + 0], 0.f);
                float a1 = fmaxf((acc0[4 * g + 1] + bs[c0 + 1]) * gs[c0 + 1], 0.f);
                float a2 = fmaxf((acc0[4 * g + 2] + bs[c0 + 2]) * gs[c0 + 2], 0.f);
                float a3 = fmaxf((acc0[4 * g + 3] + bs[c0 + 3]) * gs[c0 + 3], 0.f);
                U2 w0; w0.x = cvtpk(a0, a1); w0.y = cvtpk(a2, a3);
                *(U2*)(ob + p0 + c0) = w0;
                float c0v = fmaxf((acc1[4 * g + 0] + bs[c0 + 0]) * gs[c0 + 0], 0.f);
                float c1v = fmaxf((acc1[4 * g + 1] + bs[c0 + 1]) * gs[c0 + 1], 0.f);
                float c2v = fmaxf((acc1[4 * g + 2] + bs[c0 + 2]) * gs[c0 + 2], 0.f);
                float c3v = fmaxf((acc1[4 * g + 3] + bs[c0 + 3]) * gs[c0 + 3], 0.f);
                U2 w1; w1.x = cvtpk(c0v, c1v); w1.y = cvtpk(c2v, c3v);
                *(U2*)(ob + p1 + c0) = w1;
            }
        } else {
            float* ob = (float*)out + (size_t)b * CC * HH * WW;
            const float* rb = resid + (size_t)b * CC * HH * WW;
            #pragma unroll
            for (int reg = 0; reg < 16; ++reg) {
                int co = (reg & 3) + 8 * (reg >> 2) + 4 * half;
                int i0 = (co * HH + y0 + r0) * WW + x0 + col;
                int i1 = (co * HH + y0 + r1) * WW + x0 + col;
                float v0 = (acc0[reg] + bs[co]) * gs[co];
                float v1 = (acc1[reg] + bs[co]) * gs[co];
                ob[i0] = fmaxf(v0, 0.f) + rb[i0];
                ob[i1] = fmaxf(v1, 0.f) + rb[i1];
            }
        }
    }
}

extern "C" void kernel_launch(void* const* d_in, const int* in_sizes, int n_in,
                              void* d_out, int out_size, void* d_ws, size_t ws_size,
                              hipStream_t stream) {
    const float* x  = (const float*)d_in[0];
    const float* gv = (const float*)d_in[1];
    const float* w1 = (const float*)d_in[2];
    const float* b1 = (const float*)d_in[3];
    const float* w2 = (const float*)d_in[4];
    const float* b2 = (const float*)d_in[5];
    float* out = (float*)d_out;

    unsigned short* h1 = (unsigned short*)d_ws;          // bf16 NHWC intermediate: 64 MiB
    unsigned short* wq = h1 + (size_t)BB * HH * WW * CC; // 2 x 9216 bf16 frag tables

    wprep<<<36, 256, 0, stream>>>(w1, w2, wq);

    dim3 grid(WW / TW, HH / (TH * NT), BB);  // (8, 8, 16) = 1024 blocks x 4 tiles
    conv_mfma<true ><<<grid, 256, 0, stream>>>(x,  wq,        b1, gv, nullptr, h1);
    conv_mfma<false><<<grid, 256, 0, stream>>>(h1, wq + 9216, b2, gv, x,       out);
}